// Round 5
// baseline (441.089 us; speedup 1.0000x reference)
//
#include <hip/hip_runtime.h>
#include <hip/hip_bf16.h>

// Problem constants
#define NPAT 4096   // patches
#define EDIM 64     // embedding per head
#define NH   8      // heads
#define HE   512    // H*E
#define OUTD 64     // CIN*P^3

typedef short bf16x8 __attribute__((ext_vector_type(8)));
typedef float f32x4  __attribute__((ext_vector_type(4)));

#if __has_builtin(__builtin_amdgcn_exp2f)
#define EXP2(x) __builtin_amdgcn_exp2f(x)
#else
#define EXP2(x) exp2f(x)
#endif

__device__ __forceinline__ ushort f2bf(float f) {
    uint u = __builtin_bit_cast(uint, f);
    return (ushort)((u + 0x7FFFu + ((u >> 16) & 1u)) >> 16);
}
__device__ __forceinline__ float bf2f(ushort b) {
    return __builtin_bit_cast(float, ((uint)b) << 16);
}

// ---------------- Kernel 1: conv3d(stride4) + LN + pos -> emb fp32 [4096][64]
__global__ __launch_bounds__(64) void k_embed(
    const float* __restrict__ voxel,   // [64][64][64]
    const float* __restrict__ conv_w,  // [64][64]
    const float* __restrict__ conv_b,  // [64]
    const float* __restrict__ ln_g, const float* __restrict__ ln_b,
    const float* __restrict__ pos,     // [4096][64]
    float* __restrict__ emb)           // [4096][64]
{
    const int n = blockIdx.x;
    const int d = n >> 8, hh = (n >> 4) & 15, ww = n & 15;
    const int t = threadIdx.x;  // 0..63 (one wave)
    __shared__ float vox[64];
    __shared__ float wsm[64 * 65];  // padded stride 65 to spread banks

    for (int i = t; i < 4096; i += 64) wsm[(i >> 6) * 65 + (i & 63)] = conv_w[i];
    const int i3 = t >> 4, j3 = (t >> 2) & 3, k3 = t & 3;
    vox[t] = voxel[(d * 4 + i3) * 4096 + (hh * 4 + j3) * 64 + (ww * 4 + k3)];
    __syncthreads();

    float acc = conv_b[t];
    #pragma unroll
    for (int m = 0; m < 64; m++) acc += vox[m] * wsm[t * 65 + m];

    // LayerNorm across the 64 lanes (one wave)
    float s1 = acc, s2 = acc * acc;
    #pragma unroll
    for (int off = 1; off < 64; off <<= 1) {
        s1 += __shfl_xor(s1, off);
        s2 += __shfl_xor(s2, off);
    }
    const float mu  = s1 * (1.0f / 64.0f);
    const float var = s2 * (1.0f / 64.0f) - mu * mu;
    const float y = (acc - mu) * rsqrtf(var + 1e-5f) * ln_g[t] + ln_b[t] + pos[n * 64 + t];
    emb[n * 64 + t] = y;
}

// ---------------- Kernel 2: projections -> qk bf16 [H][N][64], vT bf16 [H][64][N]
__global__ __launch_bounds__(256) void k_proj(
    const float* __restrict__ emb,   // [4096][64]
    const float* __restrict__ wqk, const float* __restrict__ bqk,
    const float* __restrict__ wv,  const float* __restrict__ bvv,
    ushort* __restrict__ qk_bf,      // [H][4096][64]
    ushort* __restrict__ vT_bf)      // [H][64][4096]
{
    const int n0 = blockIdx.x * 16;
    const int t = threadIdx.x;  // 0..255
    __shared__ float es[16][64];
    for (int i = t; i < 16 * 64; i += 256) es[i >> 6][i & 63] = emb[n0 * 64 + i];
    __syncthreads();

    const int he0 = t, he1 = t + 256;
    const float bq0 = bqk[he0], bq1 = bqk[he1];
    const float bv0 = bvv[he0], bv1 = bvv[he1];

    for (int rc = 0; rc < 2; rc++) {
        float aq0[8], aq1[8], av0[8], av1[8];
        #pragma unroll
        for (int r = 0; r < 8; r++) { aq0[r] = bq0; aq1[r] = bq1; av0[r] = bv0; av1[r] = bv1; }
        for (int e = 0; e < 64; e++) {
            const float wq0 = wqk[e * HE + he0], wq1 = wqk[e * HE + he1];
            const float wv0 = wv [e * HE + he0], wv1 = wv [e * HE + he1];
            #pragma unroll
            for (int r = 0; r < 8; r++) {
                const float x = es[rc * 8 + r][e];
                aq0[r] += x * wq0; aq1[r] += x * wq1;
                av0[r] += x * wv0; av1[r] += x * wv1;
            }
        }
        #pragma unroll
        for (int r = 0; r < 8; r++) {
            const int n = n0 + rc * 8 + r;
            qk_bf[((he0 >> 6) * NPAT + n) * 64 + (he0 & 63)] = f2bf(aq0[r]);
            qk_bf[((he1 >> 6) * NPAT + n) * 64 + (he1 & 63)] = f2bf(aq1[r]);
            vT_bf[((he0 >> 6) * 64 + (he0 & 63)) * NPAT + n] = f2bf(av0[r]);
            vT_bf[((he1 >> 6) * 64 + (he1 & 63)) * NPAT + n] = f2bf(av1[r]);
        }
    }
}

// ---------------- Kernel 2b: q2[h][n] = sum_e qk^2
__global__ __launch_bounds__(256) void k_q2(
    const ushort* __restrict__ qk_bf, float* __restrict__ q2)
{
    const int i = blockIdx.x * 256 + threadIdx.x;  // 0..32767 = h*4096+n
    const ushort* row = qk_bf + (size_t)i * 64;
    float s = 0.0f;
    #pragma unroll
    for (int c = 0; c < 8; c++) {
        bf16x8 v = *(const bf16x8*)(row + c * 8);
        #pragma unroll
        for (int j = 0; j < 8; j++) { float f = bf2f((ushort)v[j]); s += f * f; }
    }
    q2[i] = s;
}

// ---------------- Kernel 3: fused L2-distance attention (per head, per 64-row tile)
// p_ij = exp(cc * exp(-(q2_i + q2_j - 2 q_i.q_j))), O = P V (unnormalized), Z = row-sum P
// p_lds is per-wave private: no block barrier needed, but the P write->read is a
// CROSS-LANE exchange, so pin compiler ordering with wave_barrier (0 instructions);
// the in-order DS pipe provides the HW ordering within the wave.
__global__ __launch_bounds__(256) void k_attn(
    const ushort* __restrict__ qk,   // [H][N][64] bf16
    const ushort* __restrict__ vT,   // [H][64][N] bf16
    const float* __restrict__ q2,    // [H][N]
    const float* __restrict__ alpha, // [1]
    float* __restrict__ attn)        // [N][512]
{
    const int h  = blockIdx.y;
    const int bx = blockIdx.x;          // 64-row tile
    const int tid = threadIdx.x;
    const int w  = tid >> 6;            // wave 0..3
    const int l  = tid & 63;
    const int lr = l & 15;
    const int lg = l >> 4;
    const float L2E = 1.4426950408889634f;
    const float ccl2e = alpha[0] * 0.125f * L2E;

    __shared__ ushort p_lds[4][16 * 64];  // per-wave P tile [16 rows][64 cols] bf16, XOR-swizzled

    const ushort* qkh = qk + (size_t)h * NPAT * 64;
    const ushort* vTh = vT + (size_t)h * 64 * NPAT;
    const float*  q2h = q2 + h * NPAT;

    const int row0 = bx * 64 + w * 16;

    // Q A-fragments: row = row0+lr, k = 32f + 8*lg + j
    bf16x8 aq0, aq1;
    {
        const ushort* qrow = qkh + (size_t)(row0 + lr) * 64 + 8 * lg;
        aq0 = *(const bf16x8*)(qrow);
        aq1 = *(const bf16x8*)(qrow + 32);
    }
    float nq2[4];
    #pragma unroll
    for (int r = 0; r < 4; r++) nq2[r] = q2h[row0 + 4 * lg + r];

    f32x4 acc[4];
    #pragma unroll
    for (int c = 0; c < 4; c++) acc[c] = (f32x4){0.f, 0.f, 0.f, 0.f};
    float zacc[4] = {0.f, 0.f, 0.f, 0.f};

    char* pbase = (char*)(&p_lds[w][0]);

    for (int j0 = 0; j0 < NPAT; j0 += 64) {
        // ---- QK^T for 4 col-tiles, p, stash P in LDS
        #pragma unroll
        for (int t = 0; t < 4; t++) {
            const ushort* krow = qkh + (size_t)(j0 + t * 16 + lr) * 64 + 8 * lg;
            bf16x8 bk0 = *(const bf16x8*)(krow);
            bf16x8 bk1 = *(const bf16x8*)(krow + 32);
            f32x4 s = (f32x4){0.f, 0.f, 0.f, 0.f};
            s = __builtin_amdgcn_mfma_f32_16x16x32_bf16(aq0, bk0, s, 0, 0, 0);
            s = __builtin_amdgcn_mfma_f32_16x16x32_bf16(aq1, bk1, s, 0, 0, 0);
            const float k2c = q2h[j0 + t * 16 + lr];
            #pragma unroll
            for (int r = 0; r < 4; r++) {
                const float d = nq2[r] + k2c - 2.0f * s[r];
                const float p = EXP2(ccl2e * EXP2(-L2E * d));
                zacc[r] += p;
                const int row = 4 * lg + r, col = 16 * t + lr;
                const int byteoff = row * 128 + ((col * 2) ^ ((row & 7) << 4));
                *(ushort*)(pbase + byteoff) = f2bf(p);
            }
        }
        // pin compiler ordering: all P writes before the cross-lane read-back
        __builtin_amdgcn_wave_barrier();
        // ---- read P back as A-fragments (row = lr, k-chunk = 32f + 8*lg)
        bf16x8 pa0, pa1;
        {
            char* rb = pbase + lr * 128;
            const int x = (lr & 7) << 4;
            pa0 = *(const bf16x8*)(rb + ((16 * lg) ^ x));
            pa1 = *(const bf16x8*)(rb + ((64 + 16 * lg) ^ x));
        }
        // pin ordering: reads complete (in DS pipe order) before next iter's writes
        __builtin_amdgcn_wave_barrier();
        // ---- PV: O[c-tile] += P * V
        #pragma unroll
        for (int c = 0; c < 4; c++) {
            const ushort* vrow = vTh + (size_t)(c * 16 + lr) * NPAT + j0 + 8 * lg;
            bf16x8 bv0 = *(const bf16x8*)(vrow);
            bf16x8 bv1 = *(const bf16x8*)(vrow + 32);
            acc[c] = __builtin_amdgcn_mfma_f32_16x16x32_bf16(pa0, bv0, acc[c], 0, 0, 0);
            acc[c] = __builtin_amdgcn_mfma_f32_16x16x32_bf16(pa1, bv1, acc[c], 0, 0, 0);
        }
    }

    // ---- reduce Z across the 16 col-lanes of each group, normalize, store
    #pragma unroll
    for (int r = 0; r < 4; r++) {
        float z = zacc[r];
        z += __shfl_xor(z, 1); z += __shfl_xor(z, 2);
        z += __shfl_xor(z, 4); z += __shfl_xor(z, 8);
        zacc[r] = 1.0f / z;
    }
    #pragma unroll
    for (int c = 0; c < 4; c++) {
        #pragma unroll
        for (int r = 0; r < 4; r++) {
            const int row = row0 + 4 * lg + r;
            attn[(size_t)row * HE + h * 64 + c * 16 + lr] = acc[c][r] * zacc[r];
        }
    }
}

// ---------------- Kernel 4: out = attn @ wout + bout
__global__ __launch_bounds__(256) void k_out(
    const float* __restrict__ attn,  // [4096][512]
    const float* __restrict__ wout,  // [512][64]
    const float* __restrict__ bout,  // [64]
    float* __restrict__ out)         // [4096][64]
{
    const int n0 = blockIdx.x * 16;
    const int t = threadIdx.x;
    const int c = t & 63, rg = t >> 6;
    __shared__ float sa[16][512];
    for (int i = t; i < 16 * 512; i += 256) sa[i >> 9][i & 511] = attn[(size_t)n0 * 512 + i];
    __syncthreads();
    #pragma unroll
    for (int rr = 0; rr < 4; rr++) {
        const int r = rg * 4 + rr;
        float acc = bout[c];
        for (int k = 0; k < 512; k++) acc += sa[r][k] * wout[k * 64 + c];
        out[(size_t)(n0 + r) * 64 + c] = acc;
    }
}

extern "C" void kernel_launch(void* const* d_in, const int* in_sizes, int n_in,
                              void* d_out, int out_size, void* d_ws, size_t ws_size,
                              hipStream_t stream) {
    (void)in_sizes; (void)n_in; (void)out_size; (void)ws_size;
    const float* voxel  = (const float*)d_in[0];
    const float* conv_w = (const float*)d_in[1];
    const float* conv_b = (const float*)d_in[2];
    const float* ln_g   = (const float*)d_in[3];
    const float* ln_b   = (const float*)d_in[4];
    const float* pos    = (const float*)d_in[5];
    const float* wqk    = (const float*)d_in[6];
    const float* bqk    = (const float*)d_in[7];
    const float* wv     = (const float*)d_in[8];
    const float* bvv    = (const float*)d_in[9];
    const float* alpha  = (const float*)d_in[10];
    const float* wout   = (const float*)d_in[11];
    const float* bout   = (const float*)d_in[12];
    float* out = (float*)d_out;

    char* ws = (char*)d_ws;
    float*  emb   = (float*) (ws);                                   // 1 MB
    ushort* qk_bf = (ushort*)(ws + (1u << 20));                      // 4 MB
    ushort* vT_bf = (ushort*)(ws + 5u * (1u << 20));                 // 4 MB
    float*  q2    = (float*) (ws + 9u * (1u << 20));                 // 128 KB
    float*  attn  = (float*) (ws + 9u * (1u << 20) + (128u << 10));  // 8 MB

    k_embed<<<NPAT, 64, 0, stream>>>(voxel, conv_w, conv_b, ln_g, ln_b, pos, emb);
    k_proj<<<NPAT / 16, 256, 0, stream>>>(emb, wqk, bqk, wv, bvv, qk_bf, vT_bf);
    k_q2<<<(NH * NPAT) / 256, 256, 0, stream>>>(qk_bf, q2);
    k_attn<<<dim3(NPAT / 64, NH), 256, 0, stream>>>(qk_bf, vT_bf, q2, alpha, attn);
    k_out<<<NPAT / 16, 256, 0, stream>>>(attn, wout, bout, out);
}